// Round 2
// baseline (1168.453 us; speedup 1.0000x reference)
//
#include <hip/hip_runtime.h>
#include <hip/hip_bf16.h>
#include <stdint.h>
#include <stddef.h>

#define LIN    4096
#define TOUT   4097            // 4096 + 2*28 - 56 + 1
#define NBATCH 32
#define TPAD   4416            // 28 + 4096 + 28 = 4152, padded up for tile overread
#define NT     128             // t-tile per block
#define XROWS  (NT + 56)       // 184 staged x rows per c-chunk

typedef __attribute__((ext_vector_type(8)))  short short8;
typedef __attribute__((ext_vector_type(16))) float float16;

#define XT_ELEMS ((size_t)NBATCH * TPAD * 256)
#define XT_BYTES (XT_ELEMS * 2)

// ---------------- prep 1: pad + transpose + bf16:  xT[b][tp][c] ----------------
__global__ __launch_bounds__(256) void xpose_kernel(const float* __restrict__ x,
                                                    __hip_bfloat16* __restrict__ xT) {
  const int t0  = blockIdx.x * 64;
  const int b   = blockIdx.y;
  const int tid = threadIdx.x;
  __shared__ __hip_bfloat16 tile[64 * 66];
  for (int c0 = 0; c0 < 256; c0 += 64) {
#pragma unroll
    for (int j = 0; j < 16; ++j) {
      int f = j * 256 + tid;
      int c_l = f >> 6, t_l = f & 63;            // lanes consecutive in t -> coalesced read
      float v = x[((size_t)(b * 256 + c0 + c_l)) * LIN + t0 + t_l];
      tile[t_l * 66 + c_l] = __float2bfloat16(v);
    }
    __syncthreads();
#pragma unroll
    for (int j = 0; j < 16; ++j) {
      int f = j * 256 + tid;
      int t_l = f >> 6, c_l = f & 63;            // lanes consecutive in c -> coalesced write
      xT[((size_t)(b * TPAD + 28 + t0 + t_l)) * 256 + c0 + c_l] = tile[t_l * 66 + c_l];
    }
    __syncthreads();
  }
}

// ---------------- prep 2: bf16 kernel in A-fragment order ----------------
// Kd2 flat idx = ((((l*4+cc)*4 + kk)*8 + ob)*64 + lane)*8 + e
//   where o = ob*32 + (lane&31), c = cc*64 + kk*16 + (lane>>5)*8 + e
// so a wave's A fragment (32 o-rows x 16 c) is one contiguous, coalesced 1KB chunk.
__global__ __launch_bounds__(256) void build_kd(const float* __restrict__ w,
                                                const float* __restrict__ P,
                                                __hip_bfloat16* __restrict__ Kd2) {
  const int o = blockIdx.x;
  const int c = threadIdx.x;
  __shared__ float accs[256 * 56];
  float* a = &accs[c * 56];
  for (int l = 0; l < 56; ++l) a[l] = 0.0f;
  const int base = (o * 256 + c) * 7;
#pragma unroll
  for (int k = 0; k < 7; ++k) {
    float wv  = w[base + k];
    float pos = P[base + k] + 28.0f;
    pos = fminf(fmaxf(pos, 0.0f), 55.0f);        // clamp border (matches jnp.clip)
    float lo  = floorf(pos);
    float fr  = pos - lo;
    int li = (int)lo;
    int hi = li + 1; if (hi > 55) hi = 55;
    a[li] += wv * (1.0f - fr);
    a[hi] += wv * fr;
  }
  const int cc   = c >> 6;
  const int kk   = (c >> 4) & 3;
  const int half = (c >> 3) & 1;
  const int e    = c & 7;
  const int ob   = o >> 5;
  const int lane = half * 32 + (o & 31);
  for (int l = 0; l < 56; ++l) {
    size_t idx = ((((size_t)(l * 4 + cc) * 4 + kk) * 8 + ob) * 64 + lane) * 8 + e;
    Kd2[idx] = __float2bfloat16(a[l]);
  }
}

// ---------------- main: implicit-GEMM conv, barrier-free l-loop ----------------
// block: 256 thr = 4 waves; out tile 256(o) x 128(t); wave wid owns o in [wid*64, wid*64+64)
// A: global->VGPR coalesced from Kd2 (LLC-resident), 1-step software pipeline.
// B: x tile [184 t][64 c] in LDS, XOR-8 16B-unit swizzle (conflict-free), staged per cc.
// Barriers: only around the 4 x-stagings. The 224-step MFMA loop has none.
__global__ __launch_bounds__(256, 2) void conv_mfma(const __hip_bfloat16* __restrict__ xT,
                                                    const short* __restrict__ Kd2,
                                                    const float* __restrict__ bias,
                                                    float* __restrict__ out) {
  __shared__ char smem[XROWS * 128];   // 23552 B
  char* xs = smem;

  const int tid   = threadIdx.x;
  const int t0    = blockIdx.x * NT;
  const int b     = blockIdx.y;
  const int wid   = tid >> 6;
  const int lane  = tid & 63;
  const int laneN = lane & 31;
  const int half  = lane >> 5;

  float16 acc[2][4];
#pragma unroll
  for (int i = 0; i < 2; ++i)
#pragma unroll
    for (int j = 0; j < 4; ++j) acc[i][j] = (float16)(0.0f);

  // per-wave A lane base: chunk (l*16+cc*4+kk)*4096 + (wid*2+i)*512 + lane*8
  const short* Aw = Kd2 + (wid * 2) * 512 + lane * 8;

  for (int cc = 0; cc < 4; ++cc) {
    // ---- stage x tile [184 t][64 c], swizzled ----
    {
      const size_t gbase = ((size_t)(b * TPAD + t0)) * 256 + cc * 64;
#pragma unroll
      for (int j = 0; j < 6; ++j) {
        int f = j * 256 + tid;
        if (f < XROWS * 8) {
          int r = f >> 3, u = f & 7;
          int4 v = *(const int4*)(xT + gbase + (size_t)r * 256 + u * 8);
          *(int4*)(xs + r * 128 + ((u ^ (r & 7)) << 4)) = v;
        }
      }
    }
    __syncthreads();

    // ---- software-pipelined step loop: s = l*4 + kk, no barriers ----
    short8 pf[2][2];
    {
      const short* p = Aw + ((size_t)(cc * 4) << 12);
      pf[0][0] = *(const short8*)p;
      pf[0][1] = *(const short8*)(p + 512);
    }
    for (int l = 0; l < 56; ++l) {
#pragma unroll
      for (int kk = 0; kk < 4; ++kk) {
        const int cur = kk & 1;            // (l*4+kk) & 1
        // prefetch fragments for step s+1
        {
          int ns = l * 4 + kk + 1;
          if (ns > 223) ns = 223;          // clamp: avoid OOB, value unused
          const int nl = ns >> 2, nk = ns & 3;
          const short* p = Aw + ((size_t)(nl * 16 + cc * 4 + nk) << 12);
          pf[cur ^ 1][0] = *(const short8*)p;
          pf[cur ^ 1][1] = *(const short8*)(p + 512);
        }
        const int u = (kk << 1) + half;
        short8 bfr[4];
#pragma unroll
        for (int jn = 0; jn < 4; ++jn) {
          int row = jn * 32 + laneN + l;
          bfr[jn] = *(const short8*)(xs + row * 128 + ((u ^ (row & 7)) << 4));
        }
#pragma unroll
        for (int i = 0; i < 2; ++i)
#pragma unroll
          for (int jn = 0; jn < 4; ++jn)
            acc[i][jn] = __builtin_amdgcn_mfma_f32_32x32x16_bf16(pf[cur][i], bfr[jn], acc[i][jn], 0, 0, 0);
      }
    }
    __syncthreads();   // protect xs before restaging (WAR)
  }

  // ---- epilogue: C/D layout col=lane&31, row=(reg&3)+8*(reg>>2)+4*(lane>>5) ----
#pragma unroll
  for (int i = 0; i < 2; ++i) {
#pragma unroll
    for (int jn = 0; jn < 4; ++jn) {
      int t = t0 + jn * 32 + laneN;
      if (t < TOUT) {
#pragma unroll
        for (int r = 0; r < 16; ++r) {
          int row = (r & 3) + 8 * (r >> 2) + 4 * half;
          int o = wid * 64 + i * 32 + row;
          out[((size_t)(b * 256 + o)) * TOUT + t] = acc[i][jn][r] + bias[o];
        }
      }
    }
  }
}

extern "C" void kernel_launch(void* const* d_in, const int* in_sizes, int n_in,
                              void* d_out, int out_size, void* d_ws, size_t ws_size,
                              hipStream_t stream) {
  const float* x    = (const float*)d_in[0];
  const float* w    = (const float*)d_in[1];
  const float* P    = (const float*)d_in[2];
  const float* bias = (const float*)d_in[3];
  float* out = (float*)d_out;

  __hip_bfloat16* xT = (__hip_bfloat16*)d_ws;
  __hip_bfloat16* Kd2 = (__hip_bfloat16*)((char*)d_ws + XT_BYTES);

  // zero the padded/overread regions of xT (interior overwritten by xpose_kernel)
  hipMemsetAsync(d_ws, 0, XT_BYTES, stream);

  xpose_kernel<<<dim3(LIN / 64, NBATCH), 256, 0, stream>>>(x, xT);
  build_kd<<<dim3(256), 256, 0, stream>>>(w, P, Kd2);

  conv_mfma<<<dim3((TOUT + NT - 1) / NT, NBATCH), 256, 0, stream>>>(
      xT, (const short*)Kd2, bias, out);
}